// Round 1
// baseline (67.452 us; speedup 1.0000x reference)
//
#include <hip/hip_runtime.h>

#define N_NODES 8192
#define NNZV    262144
#define E_EDGES 32768
#define PSI     64

// Stage 1: edge_feat = MLP(values) ; atomic scatter-add into agg[col]
__global__ void edge_mlp_scatter(const int* __restrict__ col,
                                 const float* __restrict__ values,
                                 const float* __restrict__ w1e,
                                 const float* __restrict__ b1e,
                                 const float* __restrict__ w2e,
                                 const float* __restrict__ b2e,
                                 float* __restrict__ agg) {
    __shared__ float sw1[PSI], sb1[PSI], sw2[PSI];
    int t = threadIdx.x;
    if (t < PSI) { sw1[t] = w1e[t]; sb1[t] = b1e[t]; sw2[t] = w2e[t]; }
    __syncthreads();
    int i = blockIdx.x * blockDim.x + t;
    if (i >= NNZV) return;
    float v = values[i];
    float f = b2e[0];
    #pragma unroll
    for (int j = 0; j < PSI; ++j) {
        float h = fmaf(v, sw1[j], sb1[j]);
        f += (h > 0.f ? h * sw2[j] : 0.f);
    }
    atomicAdd(&agg[col[i]], f);
}

// Stage 2: struct = MLP(agg) ; store struct^2
__global__ void node_mlp_sq(const float* __restrict__ agg,
                            const float* __restrict__ w1n,
                            const float* __restrict__ b1n,
                            const float* __restrict__ w2n,
                            const float* __restrict__ b2n,
                            float* __restrict__ s2) {
    __shared__ float sw1[PSI], sb1[PSI], sw2[PSI];
    int t = threadIdx.x;
    if (t < PSI) { sw1[t] = w1n[t]; sb1[t] = b1n[t]; sw2[t] = w2n[t]; }
    __syncthreads();
    int n = blockIdx.x * blockDim.x + t;
    if (n >= N_NODES) return;
    float a = agg[n];
    float s = b2n[0];
    #pragma unroll
    for (int j = 0; j < PSI; ++j) {
        float h = fmaf(a, sw1[j], sb1[j]);
        s += (h > 0.f ? h * sw2[j] : 0.f);
    }
    s2[n] = s * s;
}

// Stage 3: r[row] = sum_k adj[row,k]^2 * s2[k]  (256 MB stream — the hot kernel)
__global__ __launch_bounds__(256) void row_dot(const float* __restrict__ adj,
                                               const float* __restrict__ s2,
                                               float* __restrict__ r) {
    int row = blockIdx.x;
    const float4* arow = (const float4*)(adj + (size_t)row * N_NODES);
    const float4* s4   = (const float4*)s2;
    float acc = 0.f;
    #pragma unroll
    for (int j = 0; j < (N_NODES / 4) / 256; ++j) {
        int idx = threadIdx.x + j * 256;
        float4 a = arow[idx];
        float4 s = s4[idx];
        acc += a.x * a.x * s.x + a.y * a.y * s.y + a.z * a.z * s.z + a.w * a.w * s.w;
    }
    // wave (64-lane) shuffle reduce
    #pragma unroll
    for (int off = 32; off > 0; off >>= 1) acc += __shfl_down(acc, off, 64);
    __shared__ float part[4];
    int lane = threadIdx.x & 63, wid = threadIdx.x >> 6;
    if (lane == 0) part[wid] = acc;
    __syncthreads();
    if (threadIdx.x == 0) r[row] = part[0] + part[1] + part[2] + part[3];
}

// Stage 4: out[e] = r[src_nodes[e]]
__global__ void gather_out(const int* __restrict__ src,
                           const float* __restrict__ r,
                           float* __restrict__ out) {
    int e = blockIdx.x * blockDim.x + threadIdx.x;
    if (e < E_EDGES) out[e] = r[src[e]];
}

extern "C" void kernel_launch(void* const* d_in, const int* in_sizes, int n_in,
                              void* d_out, int out_size, void* d_ws, size_t ws_size,
                              hipStream_t stream) {
    const int*   col       = (const int*)d_in[0];
    const float* values    = (const float*)d_in[1];
    const float* adj       = (const float*)d_in[2];
    const int*   src_nodes = (const int*)d_in[3];
    const float* w1e = (const float*)d_in[4];
    const float* b1e = (const float*)d_in[5];
    const float* w2e = (const float*)d_in[6];
    const float* b2e = (const float*)d_in[7];
    const float* w1n = (const float*)d_in[8];
    const float* b1n = (const float*)d_in[9];
    const float* w2n = (const float*)d_in[10];
    const float* b2n = (const float*)d_in[11];
    float* out = (float*)d_out;

    float* agg = (float*)d_ws;                 // N floats
    float* s2  = agg + N_NODES;                // N floats
    float* r   = s2 + N_NODES;                 // N floats

    hipMemsetAsync(agg, 0, N_NODES * sizeof(float), stream);

    edge_mlp_scatter<<<NNZV / 256, 256, 0, stream>>>(col, values, w1e, b1e, w2e, b2e, agg);
    node_mlp_sq<<<N_NODES / 256, 256, 0, stream>>>(agg, w1n, b1n, w2n, b2n, s2);
    row_dot<<<N_NODES, 256, 0, stream>>>(adj, s2, r);
    gather_out<<<E_EDGES / 256, 256, 0, stream>>>(src_nodes, r, out);
}